// Round 12
// baseline (134.720 us; speedup 1.0000x reference)
//
#include <hip/hip_runtime.h>

#define N_NODES 50000
#define N_EDGES 800000
// D_S=64, D_R=16, D_E=64, D_X=16, D_P=64, NUM_CLASSES=10
// W_r: [144,64]; W_o: [144,64]; W_s: [64,10] (all row-major)
//
// Linear refactor: scores[n] = u0[n] + deg_n*u1[n] + sum_{e->n} w_e
//   w_e  = u_s[s_e] + R_a[e]@A_R          (computed in EDGE order, streamed)
//   u_s[n] = O[n]@A_S ; u0[n] = O[n]@A_O + X[n]@A_X + c1 ; u1[n] = O[n]@A_dO + c0
// with Wc = W_o@W_s [144,10], Wc2 = Wc[80:144],
//   A_O = Wc[0:64], A_X = Wc[64:80], A_S = W_r[0:64]@Wc2,
//   A_R = W_r[128:144]@Wc2, A_dO = W_r[64:128]@Wc2,
//   c0 = b_r@Wc2, c1 = b_o@W_s + b_s.
//
// Atomic placement (r9): only per-edge atomic lives in count_rank (return
// value = rank). edge_w: pos = off[r] + rank[e], no atomic.
// node_u (r10): table loads from LDS, vectorized O/X.
// edge_w (r11): VALUBusy 5% @ 1 chain/thread -> 2 edges/thread; gather
// target (u_s, 2.4 MB) is L2-resident so footprint doubling is safe
// (unlike r6's 12.8 MB O-table blowup).
//
// A-table layout in ws: [226][16] f32 (cols 10..15 zeroed):
//   rows 0..63 A_O | 64..79 A_X | 80..143 A_S | 144..159 A_R |
//   160..223 A_dO | 224 c0 | 225 c1

// ---------------------------------------------------------------------------
// Workspace layout (bytes) — end = 26,019,328 < 26,414,400 (proven in r3)
// ---------------------------------------------------------------------------
#define WS_A       ((size_t)0)          // 14,464 B
#define WS_COUNT   ((size_t)16384)      // 50000 i32 = 200,000 B
#define WS_CURSOR  ((size_t)216384)     // 1 u32 (zeroed with count memset)
#define WS_OFF     ((size_t)217088)     // 50000 i32 = 200,000 B
#define WS_RANK    ((size_t)417792)     // 800000 i32 = 3,200,000 B
#define WS_US      ((size_t)3618816)    // 50000*12 f32 = 2,400,000 B
#define WS_U01     ((size_t)6019072)    // 50000*20 f32 = 4,000,000 B
#define WS_WSORT   ((size_t)10019328)   // 800000*5 u32 = 16,000,000 B

__device__ __forceinline__ unsigned int f32_to_bf16_rne(float f) {
    unsigned int x = __float_as_uint(f);
    return (x + 0x7fffu + ((x >> 16) & 1u)) >> 16;
}

// ---------------------------------------------------------------------------
// Precompute folded weight table A — 10 blocks, redundant Wc2 in LDS
// ---------------------------------------------------------------------------
__global__ __launch_bounds__(256) void precompute_A(
    const float* __restrict__ W_r, const float* __restrict__ b_r,
    const float* __restrict__ W_o, const float* __restrict__ b_o,
    const float* __restrict__ W_s, const float* __restrict__ b_s,
    float* __restrict__ A)
{
    __shared__ float Wc2[640];  // Wc rows 80..143 (64 x 10)
    const int t = threadIdx.x;

    for (int idx = t; idx < 640; idx += 256) {
        const int row = 80 + idx / 10, c = idx % 10;
        float acc = 0.f;
        for (int j = 0; j < 64; ++j)
            acc = fmaf(W_o[row * 64 + j], W_s[j * 10 + c], acc);
        Wc2[idx] = acc;
    }
    __syncthreads();

    // work items: [0,1356) zero pads | [1356,2156) A_O/A_X | [2156,3596) A_S/A_R/A_dO
    //             [3596,3606) c0 | [3606,3616) c1
    for (int g = blockIdx.x * 256 + t; g < 3616; g += gridDim.x * 256) {
        if (g < 1356) {
            const int row = g / 6, c = 10 + g % 6;
            A[row * 16 + c] = 0.f;
        } else if (g < 2156) {
            const int i = g - 1356, row = i / 10, c = i % 10;
            float acc = 0.f;
            for (int j = 0; j < 64; ++j)
                acc = fmaf(W_o[row * 64 + j], W_s[j * 10 + c], acc);
            A[row * 16 + c] = acc;
        } else if (g < 3596) {
            const int i = g - 2156, k = i / 10, c = i % 10;
            const int wrow = (k < 64) ? k : (k < 80 ? 128 + (k - 64) : 64 + (k - 80));
            const int arow = (k < 64) ? 80 + k : (k < 80 ? 144 + (k - 64) : 160 + (k - 80));
            const float* src = W_r + (size_t)wrow * 64;
            float acc = 0.f;
            for (int m = 0; m < 64; ++m)
                acc = fmaf(src[m], Wc2[m * 10 + c], acc);
            A[arow * 16 + c] = acc;
        } else if (g < 3606) {
            const int c = g - 3596;
            float acc = 0.f;
            for (int m = 0; m < 64; ++m)
                acc = fmaf(b_r[m], Wc2[m * 10 + c], acc);
            A[224 * 16 + c] = acc;
        } else {
            const int c = g - 3606;
            float acc = b_s[c];
            for (int j = 0; j < 64; ++j)
                acc = fmaf(b_o[j], W_s[j * 10 + c], acc);
            A[225 * 16 + c] = acc;
        }
    }
}

// ---------------------------------------------------------------------------
// Per-node 10-vectors (r10 structure): thread = (node, class-PAIR),
// A staged in LDS as float2 pairs, O/X read as float4.
// ---------------------------------------------------------------------------
__global__ __launch_bounds__(256) void node_u_kernel(
    const float* __restrict__ O, const float* __restrict__ X,
    const float* __restrict__ A,
    float* __restrict__ us, float* __restrict__ u01)
{
    __shared__ float2 lA[226 * 5];  // lA[row*5+cp] = (A[row][2cp], A[row][2cp+1])
    const int t = threadIdx.x;
    for (int i = t; i < 226 * 5; i += 256) {
        const int row = i / 5, cp = i - row * 5;
        lA[i] = *reinterpret_cast<const float2*>(A + (size_t)row * 16 + 2 * cp);
    }
    __syncthreads();

    const int tid = blockIdx.x * 256 + t;
    if (tid >= N_NODES * 5) return;
    const int n = tid / 5;
    const int cp = tid - n * 5;

    float vs0 = 0.f, vs1 = 0.f, v00 = 0.f, v01 = 0.f, v10 = 0.f, v11 = 0.f;

    const float4* Ov = reinterpret_cast<const float4*>(O + (size_t)n * 64);
#pragma unroll
    for (int kc = 0; kc < 16; ++kc) {
        const float4 o4 = Ov[kc];
#pragma unroll
        for (int j = 0; j < 4; ++j) {
            const float ov = (j == 0) ? o4.x : (j == 1) ? o4.y : (j == 2) ? o4.z : o4.w;
            const int k = kc * 4 + j;
            const float2 aO = lA[k * 5 + cp];            // A_O row k
            const float2 aS = lA[(80 + k) * 5 + cp];     // A_S row k
            const float2 aD = lA[(160 + k) * 5 + cp];    // A_dO row k
            v00 = fmaf(ov, aO.x, v00); v01 = fmaf(ov, aO.y, v01);
            vs0 = fmaf(ov, aS.x, vs0); vs1 = fmaf(ov, aS.y, vs1);
            v10 = fmaf(ov, aD.x, v10); v11 = fmaf(ov, aD.y, v11);
        }
    }
    const float4* Xv = reinterpret_cast<const float4*>(X + (size_t)n * 16);
#pragma unroll
    for (int kc = 0; kc < 4; ++kc) {
        const float4 x4 = Xv[kc];
#pragma unroll
        for (int j = 0; j < 4; ++j) {
            const float xv = (j == 0) ? x4.x : (j == 1) ? x4.y : (j == 2) ? x4.z : x4.w;
            const int k = 64 + kc * 4 + j;
            const float2 aX = lA[k * 5 + cp];            // A_X row
            v00 = fmaf(xv, aX.x, v00); v01 = fmaf(xv, aX.y, v01);
        }
    }

    const float2 c0 = lA[224 * 5 + cp];
    const float2 c1 = lA[225 * 5 + cp];
    *reinterpret_cast<float2*>(us + (size_t)n * 12 + 2 * cp) = make_float2(vs0, vs1);
    *reinterpret_cast<float2*>(u01 + (size_t)n * 20 + 2 * cp) =
        make_float2(v00 + c1.x, v01 + c1.y);
    *reinterpret_cast<float2*>(u01 + (size_t)n * 20 + 10 + 2 * cp) =
        make_float2(v10 + c0.x, v11 + c0.y);
}

// ---------------------------------------------------------------------------
// Receiver histogram + rank: the atomic's return value IS the rank.
// ---------------------------------------------------------------------------
__global__ __launch_bounds__(256) void count_rank_kernel(
    const int* __restrict__ receivers, int* __restrict__ count,
    int* __restrict__ rank)
{
    const int t = blockIdx.x * 256 + threadIdx.x;
    if (t * 4 >= N_EDGES) return;
    const int4 r4 = reinterpret_cast<const int4*>(receivers)[t];
    int4 k4;
    k4.x = atomicAdd(count + r4.x, 1);
    k4.y = atomicAdd(count + r4.y, 1);
    k4.z = atomicAdd(count + r4.z, 1);
    k4.w = atomicAdd(count + r4.w, 1);
    reinterpret_cast<int4*>(rank)[t] = k4;
}

// ---------------------------------------------------------------------------
// Segment allocation, wave-aggregated: shfl prefix-sum, 1 atomic per wave.
// ---------------------------------------------------------------------------
__global__ __launch_bounds__(256) void alloc_kernel(
    const int* __restrict__ count, unsigned int* __restrict__ cursor,
    int* __restrict__ off)
{
    const int n = blockIdx.x * 256 + threadIdx.x;
    const int lane = threadIdx.x & 63;
    const int c = (n < N_NODES) ? count[n] : 0;

    int pre = c;
#pragma unroll
    for (int d = 1; d < 64; d <<= 1) {
        const int v = __shfl_up(pre, d);
        if (lane >= d) pre += v;
    }
    const int total = __shfl(pre, 63);
    int base = 0;
    if (lane == 63) base = (int)atomicAdd(cursor, (unsigned int)total);
    base = __shfl(base, 63);

    if (n < N_NODES) off[n] = base + pre - c;  // exclusive prefix
}

// ---------------------------------------------------------------------------
// Per-edge w_e = u_s[s_e] + R_a[e]@A_R -> bf16-packed to sorted slot.
// 2 edges/thread, loads breadth-first: both off/rank/u_s chains in flight;
// R_a consumed loop-wise to cap live VGPRs. No atomic.
// ---------------------------------------------------------------------------
__global__ __launch_bounds__(256) void edge_w_kernel(
    const float* __restrict__ R_a,
    const int* __restrict__ senders, const int* __restrict__ receivers,
    const int* __restrict__ rank, const int* __restrict__ off,
    const float* __restrict__ us, const float* __restrict__ A,
    unsigned int* __restrict__ wsort)   // [E][5] dwords, receiver-sorted
{
    const int e0 = (blockIdx.x * 256 + threadIdx.x) * 2;
    if (e0 >= N_EDGES) return;  // N_EDGES even

    const int2 s2 = *reinterpret_cast<const int2*>(senders + e0);
    const int2 r2 = *reinterpret_cast<const int2*>(receivers + e0);
    const int2 k2 = *reinterpret_cast<const int2*>(rank + e0);

    // both position chains in flight
    const int pos0 = off[r2.x] + k2.x;
    const int pos1 = off[r2.y] + k2.y;

    // both u_s gathers in flight (6 x 16B from L2-resident 2.4 MB table)
    const float4* U0 = reinterpret_cast<const float4*>(us + (size_t)s2.x * 12);
    const float4* U1 = reinterpret_cast<const float4*>(us + (size_t)s2.y * 12);
    const float4 ua0 = U0[0], ub0 = U0[1], uc0 = U0[2];
    const float4 ua1 = U1[0], ub1 = U1[1], uc1 = U1[2];

    float a0[10] = {ua0.x, ua0.y, ua0.z, ua0.w, ub0.x, ub0.y, ub0.z, ub0.w, uc0.x, uc0.y};
    float a1[10] = {ua1.x, ua1.y, ua1.z, ua1.w, ub1.x, ub1.y, ub1.z, ub1.w, uc1.x, uc1.y};

    // R_a for both edges (contiguous 128 B per thread), A rows are
    // wave-uniform -> SGPR operands
    const float4* Rv = reinterpret_cast<const float4*>(R_a + (size_t)e0 * 16);
#pragma unroll
    for (int kc = 0; kc < 4; ++kc) {
        const float4 b4 = Rv[kc];
        const float4 c4 = Rv[4 + kc];
        const float* A0 = A + (size_t)(144 + kc * 4) * 16;
#pragma unroll
        for (int c = 0; c < 10; ++c) {
            a0[c] = fmaf(b4.x, A0[c], a0[c]);
            a1[c] = fmaf(c4.x, A0[c], a1[c]);
        }
#pragma unroll
        for (int c = 0; c < 10; ++c) {
            a0[c] = fmaf(b4.y, A0[16 + c], a0[c]);
            a1[c] = fmaf(c4.y, A0[16 + c], a1[c]);
        }
#pragma unroll
        for (int c = 0; c < 10; ++c) {
            a0[c] = fmaf(b4.z, A0[32 + c], a0[c]);
            a1[c] = fmaf(c4.z, A0[32 + c], a1[c]);
        }
#pragma unroll
        for (int c = 0; c < 10; ++c) {
            a0[c] = fmaf(b4.w, A0[48 + c], a0[c]);
            a1[c] = fmaf(c4.w, A0[48 + c], a1[c]);
        }
    }

    unsigned int* wp0 = wsort + (size_t)pos0 * 5;
    wp0[0] = f32_to_bf16_rne(a0[0]) | (f32_to_bf16_rne(a0[1]) << 16);
    wp0[1] = f32_to_bf16_rne(a0[2]) | (f32_to_bf16_rne(a0[3]) << 16);
    wp0[2] = f32_to_bf16_rne(a0[4]) | (f32_to_bf16_rne(a0[5]) << 16);
    wp0[3] = f32_to_bf16_rne(a0[6]) | (f32_to_bf16_rne(a0[7]) << 16);
    wp0[4] = f32_to_bf16_rne(a0[8]) | (f32_to_bf16_rne(a0[9]) << 16);

    unsigned int* wp1 = wsort + (size_t)pos1 * 5;
    wp1[0] = f32_to_bf16_rne(a1[0]) | (f32_to_bf16_rne(a1[1]) << 16);
    wp1[1] = f32_to_bf16_rne(a1[2]) | (f32_to_bf16_rne(a1[3]) << 16);
    wp1[2] = f32_to_bf16_rne(a1[4]) | (f32_to_bf16_rne(a1[5]) << 16);
    wp1[3] = f32_to_bf16_rne(a1[6]) | (f32_to_bf16_rne(a1[7]) << 16);
    wp1[4] = f32_to_bf16_rne(a1[8]) | (f32_to_bf16_rne(a1[9]) << 16);
}

// ---------------------------------------------------------------------------
// Node scores: thread = (node, class-slot c<16). w read as a PURE SEQUENTIAL
// stream (receiver-sorted). 4-deep unroll, 4 accumulators. 16-lane softmax.
// ---------------------------------------------------------------------------
__global__ __launch_bounds__(256) void node_score_kernel(
    const float* __restrict__ u01,
    const int* __restrict__ off, const int* __restrict__ count,
    const unsigned int* __restrict__ w,   // [E][5] dwords, receiver-sorted
    float* __restrict__ out)
{
    const int tid = blockIdx.x * 256 + threadIdx.x;
    const int n = tid >> 4;
    const int c = tid & 15;
    if (n >= N_NODES) return;

    const int cc = (c < 10) ? c : 0;  // safe column for idle lanes
    const int half = cc >> 1;
    const int sh = (cc & 1) * 16;

    const int beg = off[n];
    const int dge = count[n];
    const int end = beg + dge;
    float sc = u01[(size_t)n * 20 + cc] + (float)dge * u01[(size_t)n * 20 + 10 + cc];

    float s0 = 0.f, s1 = 0.f, s2 = 0.f, s3 = 0.f;
    int i = beg;
    for (; i + 3 < end; i += 4) {
        const unsigned int v0 = w[(size_t)(i + 0) * 5 + half];
        const unsigned int v1 = w[(size_t)(i + 1) * 5 + half];
        const unsigned int v2 = w[(size_t)(i + 2) * 5 + half];
        const unsigned int v3 = w[(size_t)(i + 3) * 5 + half];
        s0 += __uint_as_float((v0 >> sh) << 16);
        s1 += __uint_as_float((v1 >> sh) << 16);
        s2 += __uint_as_float((v2 >> sh) << 16);
        s3 += __uint_as_float((v3 >> sh) << 16);
    }
    for (; i < end; ++i) {
        const unsigned int v = w[(size_t)i * 5 + half];
        s0 += __uint_as_float((v >> sh) << 16);
    }
    sc += (s0 + s1) + (s2 + s3);

    // softmax over the 10 active lanes of this 16-lane group
    float m = (c < 10) ? sc : -3.0e38f;
#pragma unroll
    for (int d = 1; d < 16; d <<= 1) m = fmaxf(m, __shfl_xor(m, d, 16));
    const float ex = (c < 10) ? __expf(sc - m) : 0.f;
    float sum = ex;
#pragma unroll
    for (int d = 1; d < 16; d <<= 1) sum += __shfl_xor(sum, d, 16);
    if (c < 10) out[(size_t)n * 10 + c] = ex / sum;
}

extern "C" void kernel_launch(void* const* d_in, const int* in_sizes, int n_in,
                              void* d_out, int out_size, void* d_ws, size_t ws_size,
                              hipStream_t stream)
{
    const float* O    = (const float*)d_in[0];
    const float* X    = (const float*)d_in[1];
    const float* R_a  = (const float*)d_in[2];
    const int* senders   = (const int*)d_in[3];
    const int* receivers = (const int*)d_in[4];
    const float* W_r  = (const float*)d_in[5];
    const float* b_r  = (const float*)d_in[6];
    const float* W_o  = (const float*)d_in[7];
    const float* b_o  = (const float*)d_in[8];
    const float* W_s  = (const float*)d_in[9];
    const float* b_s  = (const float*)d_in[10];
    float* out = (float*)d_out;
    char* ws = (char*)d_ws;

    float* A      = (float*)(ws + WS_A);
    int* count    = (int*)(ws + WS_COUNT);
    unsigned int* cursor = (unsigned int*)(ws + WS_CURSOR);
    int* off      = (int*)(ws + WS_OFF);
    int* rank     = (int*)(ws + WS_RANK);
    float* us     = (float*)(ws + WS_US);
    float* u01    = (float*)(ws + WS_U01);
    unsigned int* wsort = (unsigned int*)(ws + WS_WSORT);

    // zero count histogram + cursor (adjacent) in one memset
    hipMemsetAsync(count, 0, (size_t)(200000 + 4 + 384), stream);

    precompute_A<<<10, 256, 0, stream>>>(W_r, b_r, W_o, b_o, W_s, b_s, A);

    count_rank_kernel<<<(N_EDGES / 4 + 255) / 256, 256, 0, stream>>>(
        receivers, count, rank);

    alloc_kernel<<<(N_NODES + 255) / 256, 256, 0, stream>>>(count, cursor, off);

    node_u_kernel<<<(N_NODES * 5 + 255) / 256, 256, 0, stream>>>(O, X, A, us, u01);

    edge_w_kernel<<<(N_EDGES / 2 + 255) / 256, 256, 0, stream>>>(
        R_a, senders, receivers, rank, off, us, A, wsort);

    node_score_kernel<<<(N_NODES * 16 + 255) / 256, 256, 0, stream>>>(
        u01, off, count, wsort, out);
}